// Round 7
// baseline (299.598 us; speedup 1.0000x reference)
//
#include <hip/hip_runtime.h>
#include <math.h>

// UNISURF renderer, MI355X — MFMA fp16 2-pass, occupancy edition.
// One wave per ray; 4 rays / 256-thread block. Heavy evals (64 samples x
// 128->128->heads MLP) on v_mfma_f32_16x16x32_f16, A split fp16 hi+lo.
// R6 -> R7: m-split (two 32-sample halves) cuts live VGPRs (acc[2][4] +
// heads[2][4]x4 + A[2]) to target 3 waves/SIMD; sH1 removed (secant reuses
// sRed); __launch_bounds__(256,3) pins VGPR <= ~170. Numerics unchanged.
//
// Verified fragment layout (R5/R6 passed):
//   A: row = lane&15,  k = 4*(lane>>4) + (e&3) + 16*(e>>2)   (e = 0..7)
//   B: col = lane&15,  same k-map
//   C: col = lane&15,  row = 4*(lane>>4) + reg

#define HID 128
#define NEARF 0.8f
#define FARF  1.8f

typedef __attribute__((ext_vector_type(8))) _Float16 half8;
typedef __attribute__((ext_vector_type(4))) float f32x4;

__device__ __forceinline__ float sigmoidf_(float x) { return 1.0f / (1.0f + expf(-x)); }

// 64-sample MLP eval on MFMA, processed as two 32-sample halves (mh).
// dA0..3 = depth of sample (mt*16 + lane&15), mt = mh*2 + mt2.
// f_out = raw logit (no bo). If RGB, rgb_out = feat@Wc partials.
template<bool RGB>
__device__ __forceinline__ void eval64(
    const float* __restrict__ su, const float* __restrict__ sv,
    const _Float16* __restrict__ sW2F,
    const float* __restrict__ sB2, const float* __restrict__ sWo,
    const float* __restrict__ sWc, float* __restrict__ sred,
    float dA0, float dA1, float dA2, float dA3, int lane,
    float& f_out, float* rgb_out)
{
    const int g = lane >> 4, nl = lane & 15;

#pragma unroll
    for (int mh = 0; mh < 2; ++mh) {
        float pl[2][4], p0[2][4], p1[2][4], p2[2][4];
#pragma unroll
        for (int mt2 = 0; mt2 < 2; ++mt2)
#pragma unroll
            for (int r = 0; r < 4; ++r) {
                pl[mt2][r] = 0.f;
                if (RGB) { p0[mt2][r] = 0.f; p1[mt2][r] = 0.f; p2[mt2][r] = 0.f; }
            }

#pragma unroll
        for (int nh = 0; nh < 2; ++nh) {
            f32x4 acc[2][4];
#pragma unroll
            for (int mt2 = 0; mt2 < 2; ++mt2)
#pragma unroll
                for (int nt = 0; nt < 4; ++nt) acc[mt2][nt] = (f32x4){0.f, 0.f, 0.f, 0.f};

#pragma unroll
            for (int kt = 0; kt < 4; ++kt) {
                const float* uk = su + kt * 32 + 4 * g;
                const float* vk = sv + kt * 32 + 4 * g;
                const float4 u0 = *reinterpret_cast<const float4*>(uk);
                const float4 u1 = *reinterpret_cast<const float4*>(uk + 16);
                const float4 v0 = *reinterpret_cast<const float4*>(vk);
                const float4 v1 = *reinterpret_cast<const float4*>(vk + 16);
                const float ue[8] = {u0.x, u0.y, u0.z, u0.w, u1.x, u1.y, u1.z, u1.w};
                const float ve[8] = {v0.x, v0.y, v0.z, v0.w, v1.x, v1.y, v1.z, v1.w};
                half8 Ah[2], Al[2];
#pragma unroll
                for (int mt2 = 0; mt2 < 2; ++mt2) {
                    const int MT = mh * 2 + mt2;
                    const float d = (MT == 0) ? dA0 : (MT == 1) ? dA1 : (MT == 2) ? dA2 : dA3;
#pragma unroll
                    for (int e = 0; e < 8; ++e) {
                        const float h = fmaxf(fmaf(d, ve[e], ue[e]), 0.f);
                        const _Float16 hh = (_Float16)h;
                        Ah[mt2][e] = hh;
                        Al[mt2][e] = (_Float16)(h - (float)hh);
                    }
                }
#pragma unroll
                for (int nt = 0; nt < 4; ++nt) {
                    const int frag = (kt * 8 + nh * 4 + nt) * 64 + lane;
                    const half8 B = *reinterpret_cast<const half8*>(&sW2F[frag * 8]);
#pragma unroll
                    for (int mt2 = 0; mt2 < 2; ++mt2) {
                        acc[mt2][nt] = __builtin_amdgcn_mfma_f32_16x16x32_f16(Ah[mt2], B, acc[mt2][nt], 0, 0, 0);
                        acc[mt2][nt] = __builtin_amdgcn_mfma_f32_16x16x32_f16(Al[mt2], B, acc[mt2][nt], 0, 0, 0);
                    }
                }
            }
            // fused epilogue for this N-half
#pragma unroll
            for (int nt = 0; nt < 4; ++nt) {
                const int j = (nh * 4 + nt) * 16 + nl;
                const float b2l = sB2[j], wol = sWo[j];
                float wc0 = 0.f, wc1 = 0.f, wc2 = 0.f;
                if (RGB) { wc0 = sWc[j * 3 + 0]; wc1 = sWc[j * 3 + 1]; wc2 = sWc[j * 3 + 2]; }
#pragma unroll
                for (int mt2 = 0; mt2 < 2; ++mt2)
#pragma unroll
                    for (int r = 0; r < 4; ++r) {
                        const float h2 = fmaxf(acc[mt2][nt][r] + b2l, 0.f);
                        pl[mt2][r] = fmaf(h2, wol, pl[mt2][r]);
                        if (RGB) {
                            p0[mt2][r] = fmaf(h2, wc0, p0[mt2][r]);
                            p1[mt2][r] = fmaf(h2, wc1, p1[mt2][r]);
                            p2[mt2][r] = fmaf(h2, wc2, p2[mt2][r]);
                        }
                    }
            }
        }

        // reduce over the 16 lanes sharing a row-group (j varies across them)
#pragma unroll
        for (int off = 1; off < 16; off <<= 1) {
#pragma unroll
            for (int mt2 = 0; mt2 < 2; ++mt2)
#pragma unroll
                for (int r = 0; r < 4; ++r) {
                    pl[mt2][r] += __shfl_xor(pl[mt2][r], off);
                    if (RGB) {
                        p0[mt2][r] += __shfl_xor(p0[mt2][r], off);
                        p1[mt2][r] += __shfl_xor(p1[mt2][r], off);
                        p2[mt2][r] += __shfl_xor(p2[mt2][r], off);
                    }
                }
        }
        // scatter to lane order via LDS (row m = mh*32 + mt2*16 + 4*g + r)
        if (nl == 0) {
#pragma unroll
            for (int mt2 = 0; mt2 < 2; ++mt2)
#pragma unroll
                for (int r = 0; r < 4; ++r) {
                    const int m = mh * 32 + mt2 * 16 + 4 * g + r;
                    sred[m] = pl[mt2][r];
                    if (RGB) { sred[64 + m] = p0[mt2][r]; sred[128 + m] = p1[mt2][r]; sred[192 + m] = p2[mt2][r]; }
                }
        }
    }
    f_out = sred[lane];
    if (RGB) { rgb_out[0] = sred[64 + lane]; rgb_out[1] = sred[128 + lane]; rgb_out[2] = sred[192 + lane]; }
}

extern "C" __global__ void __launch_bounds__(256, 3)
unisurf_mfma_kernel(
    const float* __restrict__ raysDir, const float* __restrict__ raysOrg,
    const float* __restrict__ W1, const float* __restrict__ b1,
    const float* __restrict__ W2, const float* __restrict__ b2,
    const float* __restrict__ Wo, const float* __restrict__ bo,
    const float* __restrict__ Wc, const float* __restrict__ bc,
    const int* __restrict__ itp,
    float* __restrict__ outRGB, float* __restrict__ outD, float* __restrict__ outM,
    int nRays)
{
    __shared__ __align__(16) _Float16 sW2F[2048 * 8];   // B-frag layout fp16 (32KB)
    __shared__ __align__(16) float sU[4][HID];
    __shared__ __align__(16) float sV[4][HID];
    __shared__ __align__(16) float sB2[HID];
    __shared__ __align__(16) float sWoS[HID];
    __shared__ __align__(16) float sWc[HID * 3];
    __shared__ __align__(16) float sRed[4][256];

    const int tid = threadIdx.x;
    // ---- stage W2 into MFMA B-fragment order, fp16 -------------------------
    for (int s = tid; s < 2048; s += 256) {
        const int ln = s & 63, ntg = (s >> 6) & 7, kt = s >> 9;
        const int n = ntg * 16 + (ln & 15), gg = ln >> 4;
        half8 hp;
#pragma unroll
        for (int e = 0; e < 8; ++e) {
            const int k = kt * 32 + 4 * gg + (e & 3) + ((e >> 2) << 4);
            hp[e] = (_Float16)W2[k * HID + n];
        }
        *reinterpret_cast<half8*>(&sW2F[s * 8]) = hp;
    }
    if (tid < HID) { sB2[tid] = b2[tid]; sWoS[tid] = Wo[tid]; }
    for (int i = tid; i < HID * 3; i += 256) sWc[i] = Wc[i];
    __syncthreads();

    const int w = tid >> 6, lane = tid & 63, nl = lane & 15;
    const int ray = blockIdx.x * 4 + w;
    if (ray >= nRays) return;

    // ---- per-ray setup -----------------------------------------------------
    const float ox = raysOrg[ray * 3 + 0], oy = raysOrg[ray * 3 + 1], oz = raysOrg[ray * 3 + 2];
    const float dx = raysDir[ray * 3 + 0], dy = raysDir[ray * 3 + 1], dz = raysDir[ray * 3 + 2];
    const float nrm = sqrtf(dx * dx + dy * dy + dz * dz);
    const float rdx = dx / nrm, rdy = dy / nrm, rdz = dz / nrm;
    const float bo0 = bo[0];
    const float ST = 1.0f / 127.0f;

    float* su = sU[w];
    float* sv = sV[w];
    float* sred = sRed[w];
    for (int k = lane; k < HID; k += 64) {
        const float w1x = W1[k], w1y = W1[HID + k], w1z = W1[2 * HID + k];
        su[k] = ox * w1x + oy * w1y + oz * w1z + b1[k];
        sv[k] = rdx * w1x + rdy * w1y + rdz * w1z;
    }

    // ---- marching: chunk A (samples 0..63) ---------------------------------
    float fA;
    {
        float lg;
        eval64<false>(su, sv, sW2F, sB2, sWoS, sWc, sred,
                      NEARF + (float)(0 * 16 + nl) * ST, NEARF + (float)(1 * 16 + nl) * ST,
                      NEARF + (float)(2 * 16 + nl) * ST, NEARF + (float)(3 * 16 + nl) * ST,
                      lane, lg, nullptr);
        fA = sigmoidf_(lg + bo0) - 0.5f;
    }
    const float f0 = __shfl(fA, 0);
    const float fAn = __shfl_down(fA, 1);
    const bool crossA = (lane < 63) && (fA * fAn < 0.f);
    const unsigned long long balA = __ballot(crossA);

    int idx = 0; float f_lo = 0.f, f_hi = 0.f; bool haschange = false;
    if (balA) {
        const int l = __ffsll(balA) - 1;
        idx = l; f_lo = __shfl(fA, l); f_hi = __shfl(fA, l + 1); haschange = true;
    } else if (f0 < 0.f) {
        // ---- chunk B (samples 64..127) -------------------------------------
        float fB;
        {
            float lg;
            const float b0 = NEARF + 64.0f * ST;
            eval64<false>(su, sv, sW2F, sB2, sWoS, sWc, sred,
                          b0 + (float)(0 * 16 + nl) * ST, b0 + (float)(1 * 16 + nl) * ST,
                          b0 + (float)(2 * 16 + nl) * ST, b0 + (float)(3 * 16 + nl) * ST,
                          lane, lg, nullptr);
            fB = sigmoidf_(lg + bo0) - 0.5f;
        }
        float fprev = __shfl_up(fB, 1);
        const float fA63 = __shfl(fA, 63);
        if (lane == 0) fprev = fA63;
        const bool crossB = (fprev * fB < 0.f);   // pair s = 63 + lane
        const unsigned long long balB = __ballot(crossB);
        if (balB) {
            const int l = __ffsll(balB) - 1;
            idx = 63 + l; f_lo = __shfl(fprev, l); f_hi = __shfl(fB, l); haschange = true;
        }
    }

    // ---- secant refinement (wave-uniform; f32, W2 from global/L2) ----------
    float d_i;
    bool objmask = false;
    if (f0 >= 0.f) {
        d_i = 0.f;
    } else if (haschange && (f_lo < 0.f)) {
        float dlo = NEARF + (float)idx * ST;
        float dhi = NEARF + (float)(idx + 1) * ST;
        float flo = f_lo, fhi = f_hi;
        for (int itn = 0; itn < 8; ++itn) {
            float den = fhi - flo;
            if (fabsf(den) < 1e-12f) den = 1e-12f;
            const float dmid = dlo - flo * (dhi - dlo) / den;
            for (int k = lane; k < HID; k += 64)
                sred[k] = fmaxf(fmaf(dmid, sv[k], su[k]), 0.f);
            asm volatile("s_waitcnt lgkmcnt(0)" ::: "memory");
            __builtin_amdgcn_sched_barrier(0);
            float a0 = 0.f, a1 = 0.f;
#pragma unroll 4
            for (int k = 0; k < HID; ++k) {
                const float hk = sred[k];
                a0 = fmaf(hk, W2[k * HID + lane], a0);
                a1 = fmaf(hk, W2[k * HID + lane + 64], a1);
            }
            const float h2a = fmaxf(a0 + sB2[lane], 0.f);
            const float h2b = fmaxf(a1 + sB2[lane + 64], 0.f);
            float part = h2a * sWoS[lane] + h2b * sWoS[lane + 64];
#pragma unroll
            for (int off = 32; off; off >>= 1) part += __shfl_xor(part, off);
            const float fmid = sigmoidf_(part + bo0) - 0.5f;
            if (fmid < 0.f) { dlo = dmid; flo = fmid; }
            else            { dhi = dmid; fhi = fmid; }
        }
        float den = fhi - flo;
        if (fabsf(den) < 1e-12f) den = 1e-12f;
        d_i = dlo - flo * (dhi - dlo) / den;
        objmask = true;
    } else {
        d_i = __builtin_inff();
    }

    // ---- render: 64 samples, lane = sample ---------------------------------
    const int it = itp[0];
    const float delta = fmaxf(0.1f * expf(-2e-5f * (float)it), 0.01f);
    const float dsafe = objmask ? d_i : 1.0f;
    const float dnp = fmaxf(dsafe - delta, NEARF);
    const float dfp = fminf(dsafe + delta, FARF);
    const float t = (float)lane * (1.0f / 63.0f);
    const float depth = objmask ? (dnp * (1.f - t) + dfp * t)
                                : (NEARF * (1.f - t) + FARF * t);

    float lg, rgbacc[3];
    {
        const float dR0 = __shfl(depth, 0 * 16 + nl);
        const float dR1 = __shfl(depth, 1 * 16 + nl);
        const float dR2 = __shfl(depth, 2 * 16 + nl);
        const float dR3 = __shfl(depth, 3 * 16 + nl);
        eval64<true>(su, sv, sW2F, sB2, sWoS, sWc, sred,
                     dR0, dR1, dR2, dR3, lane, lg, rgbacc);
    }
    const float alpha = sigmoidf_(lg + bo0);
    float rc[3];
#pragma unroll
    for (int c = 0; c < 3; ++c) {
        const float x = rgbacc[c]
            + rdx * Wc[128 * 3 + c] + rdy * Wc[129 * 3 + c] + rdz * Wc[130 * 3 + c]
            + bc[c];
        rc[c] = sigmoidf_(x);
    }

    // transmittance: exclusive prefix product of (1 - alpha + 1e-6)
    const float om = 1.f - alpha + 1e-6f;
    float incl = om;
#pragma unroll
    for (int off = 1; off < 64; off <<= 1) {
        const float p = __shfl_up(incl, off);
        if (lane >= off) incl *= p;
    }
    float trans = __shfl_up(incl, 1);
    if (lane == 0) trans = 1.f;
    const float wgt = alpha * trans;

    float s0 = wgt * rc[0], s1 = wgt * rc[1], s2 = wgt * rc[2], sd = wgt * depth;
#pragma unroll
    for (int off = 32; off; off >>= 1) {
        s0 += __shfl_xor(s0, off);
        s1 += __shfl_xor(s1, off);
        s2 += __shfl_xor(s2, off);
        sd += __shfl_xor(sd, off);
    }
    if (lane == 0) {
        outRGB[ray * 3 + 0] = s0;
        outRGB[ray * 3 + 1] = s1;
        outRGB[ray * 3 + 2] = s2;
        outD[ray] = sd;
        outM[ray] = objmask ? 1.f : 0.f;
    }
}

extern "C" void kernel_launch(void* const* d_in, const int* in_sizes, int n_in,
                              void* d_out, int out_size, void* d_ws, size_t ws_size,
                              hipStream_t stream) {
    (void)n_in; (void)out_size; (void)d_ws; (void)ws_size;
    const int R = in_sizes[0] / 3;
    float* out = reinterpret_cast<float*>(d_out);
    dim3 grid((R + 3) / 4), block(256);
    hipLaunchKernelGGL(unisurf_mfma_kernel, grid, block, 0, stream,
        (const float*)d_in[0], (const float*)d_in[1], (const float*)d_in[2],
        (const float*)d_in[3], (const float*)d_in[4], (const float*)d_in[5],
        (const float*)d_in[6], (const float*)d_in[7], (const float*)d_in[8],
        (const float*)d_in[9], (const int*)d_in[10],
        out, out + 3 * (size_t)R, out + 4 * (size_t)R, R);
}